// Round 4
// baseline (5625.758 us; speedup 1.0000x reference)
//
#include <hip/hip_runtime.h>
#include <stdint.h>

#define B_Q     4096
#define N_SLOTS 32768
#define KD      128
#define BM      128
#define BN      128
#define NSPLIT  32
#define NCHUNK  (N_SLOTS / NSPLIT)   // 1024
#define NT_BLK  (NCHUNK / BN)        // 8
#define CAND_CAP (1 << 21)           // 2M candidates
#define MARGIN  0.25f

typedef __bf16 bf16x8 __attribute__((ext_vector_type(8)));
typedef float  f32x4  __attribute__((ext_vector_type(4)));

// ---- bf16 RNE ----
__device__ __forceinline__ unsigned short f2bf(float f) {
    unsigned u = __float_as_uint(f);
    unsigned r = u + 0x7FFFu + ((u >> 16) & 1u);
    return (unsigned short)(r >> 16);
}

// ordered-float: monotone f32 <-> u32
__device__ __forceinline__ unsigned int ord_f32(float f) {
    unsigned int u = __float_as_uint(f);
    return (u & 0x80000000u) ? ~u : (u | 0x80000000u);
}
__device__ __forceinline__ float ord_inv(unsigned int u) {
    unsigned int b = (u & 0x80000000u) ? (u & 0x7FFFFFFFu) : ~u;
    return __uint_as_float(b);
}

__device__ __forceinline__ unsigned long long shfl_xor_u64(unsigned long long v, int mask, int width) {
    unsigned int lo = (unsigned int)v, hi = (unsigned int)(v >> 32);
    lo = __shfl_xor(lo, mask, width);
    hi = __shfl_xor(hi, mask, width);
    return ((unsigned long long)hi << 32) | lo;
}

__device__ __forceinline__ void gload_lds16(const void* g, void* l) {
    __builtin_amdgcn_global_load_lds(
        (const __attribute__((address_space(1))) unsigned int*)g,
        (__attribute__((address_space(3))) unsigned int*)l, 16, 0, 0);
}

// ---------------- prep: K -> normalized bf16; Q -> bf16 ----------------
__global__ void prep_kernel(const float* __restrict__ Q, const float* __restrict__ Kb,
                            unsigned short* __restrict__ qhi, unsigned short* __restrict__ khi) {
    const int wid  = blockIdx.x * 4 + (threadIdx.x >> 6);
    const int lane = threadIdx.x & 63;
    const bool isK = wid < N_SLOTS;
    const int row  = isK ? wid : wid - N_SLOTS;
    const float* src = isK ? Kb : Q;
    float2 v = reinterpret_cast<const float2*>(src + (size_t)row * KD)[lane];
    float scale = 1.0f;
    if (isK) {
        float ss = v.x * v.x + v.y * v.y;
        #pragma unroll
        for (int off = 32; off; off >>= 1) ss += __shfl_xor(ss, off);
        scale = 1.0f / fmaxf(sqrtf(ss), 1e-12f);
    }
    unsigned short hx = f2bf(v.x * scale), hy = f2bf(v.y * scale);
    unsigned short* dh = isK ? khi : qhi;
    ((unsigned int*)(dh + (size_t)row * KD))[lane] = (unsigned int)hx | ((unsigned int)hy << 16);
}

// ---------------- pass 1: hi-only bf16 GEMM + candidate collection ----------------
// grid (32, 32), block 256 = 4 waves (2x2 quadrants of 64x64). Q frags in registers.
// K tile [128 n-rows][128 k] bf16 in LDS (32 KB); 16B slot s of row r holds logical
// chunk s^(r&7) -> frag ds_read_b128 spreads 64 lanes evenly over 8 superbanks.
__global__ __launch_bounds__(256, 2) void pass1_kernel(
    const unsigned short* __restrict__ qhi, const unsigned short* __restrict__ khi,
    unsigned int* __restrict__ glb, int* __restrict__ cnt, unsigned int* __restrict__ cands)
{
    __shared__ unsigned char lds[32768];

    const int tid  = threadIdx.x;
    const int lane = tid & 63;
    const int w    = tid >> 6;
    const int wr   = w >> 1;
    const int wc   = w & 1;
    const int q0   = blockIdx.x * BM;
    const int n0   = blockIdx.y * NCHUNK;
    const int l15  = lane & 15;
    const int lg   = lane >> 4;

    // running lower bounds on final hi-max per owned row; seed from glb (benign races)
    float L[16];
    #pragma unroll
    for (int i = 0; i < 4; ++i)
        #pragma unroll
        for (int r = 0; r < 4; ++r) {
            const int row = q0 + wr * 64 + i * 16 + lg * 4 + r;
            const unsigned int g = glb[row];
            L[i * 4 + r] = g ? ord_inv(g) : -1e30f;
        }

    // Q fragments in registers: row = q0+wr*64+i*16+l15, k = kc*32 + lg*8 .. +8
    bf16x8 aq[4][4];
    #pragma unroll
    for (int i = 0; i < 4; ++i)
        #pragma unroll
        for (int kc = 0; kc < 4; ++kc)
            aq[i][kc] = *(const bf16x8*)(qhi + (size_t)(q0 + wr * 64 + i * 16 + l15) * KD
                                         + kc * 32 + lg * 8);

    for (int t = 0; t < NT_BLK; ++t) {
        const int nb = n0 + t * BN;
        __syncthreads();                 // previous tile's reads done
        #pragma unroll
        for (int it = 0; it < 8; ++it) { // stage K tile: 32 KB, 8 chunks/thread
            const int ch = it * 256 + tid;
            const int r  = ch >> 4;
            const int lchunk = (ch & 15) ^ (r & 7);   // inverse swizzle on source
            gload_lds16(khi + (size_t)(nb + r) * KD + lchunk * 8, &lds[ch * 16]);
        }
        __syncthreads();

        f32x4 acc[4][4];
        #pragma unroll
        for (int i = 0; i < 4; ++i)
            #pragma unroll
            for (int j = 0; j < 4; ++j) {
                acc[i][j][0] = 0.f; acc[i][j][1] = 0.f;
                acc[i][j][2] = 0.f; acc[i][j][3] = 0.f;
            }

        #pragma unroll
        for (int kc = 0; kc < 4; ++kc) {
            bf16x8 bh[4];
            #pragma unroll
            for (int j = 0; j < 4; ++j) {
                const int rb = wc * 64 + j * 16 + l15;
                const int ps = (kc * 4 + lg) ^ (rb & 7);   // physical 16B slot
                bh[j] = *(const bf16x8*)&lds[rb * 256 + ps * 16];
            }
            #pragma unroll
            for (int i = 0; i < 4; ++i)
                #pragma unroll
                for (int j = 0; j < 4; ++j)
                    acc[i][j] = __builtin_amdgcn_mfma_f32_16x16x32_bf16(aq[i][kc], bh[j], acc[i][j], 0, 0, 0);
        }

        // two-phase epilogue: (a) fold L, (b) butterfly-share, (c) append-scan
        #pragma unroll
        for (int i = 0; i < 4; ++i)
            #pragma unroll
            for (int r = 0; r < 4; ++r) {
                float Le = L[i * 4 + r];
                #pragma unroll
                for (int j = 0; j < 4; ++j) Le = fmaxf(Le, acc[i][j][r]);
                L[i * 4 + r] = Le;
            }
        #pragma unroll
        for (int e = 0; e < 16; ++e)
            #pragma unroll
            for (int m = 8; m; m >>= 1)
                L[e] = fmaxf(L[e], __shfl_xor(L[e], m, 16));

        #pragma unroll
        for (int i = 0; i < 4; ++i)
            #pragma unroll
            for (int r = 0; r < 4; ++r) {
                const float th  = L[i * 4 + r] - MARGIN;
                const int   row = q0 + wr * 64 + i * 16 + lg * 4 + r;
                #pragma unroll
                for (int j = 0; j < 4; ++j) {
                    if (acc[i][j][r] > th) {
                        const int n = nb + wc * 64 + j * 16 + l15;
                        const int idx = atomicAdd(cnt, 1);
                        if (idx < CAND_CAP)
                            cands[idx] = ((unsigned int)row << 15) | (unsigned int)n;
                    }
                }
            }
    }

    // publish row bounds for later blocks
    #pragma unroll
    for (int i = 0; i < 4; ++i)
        #pragma unroll
        for (int r = 0; r < 4; ++r)
            if (l15 == 0) {
                const int row = q0 + wr * 64 + i * 16 + lg * 4 + r;
                atomicMax(&glb[row], ord_f32(L[i * 4 + r]));
            }
}

// ---------------- pass 2: exact fp32 rescore of candidates ----------------
__global__ void pass2_kernel(const float* __restrict__ Q, const float* __restrict__ Kb,
                             const int* __restrict__ cnt, const unsigned int* __restrict__ cands,
                             unsigned long long* __restrict__ best2) {
    const int lane = threadIdx.x & 63;
    const int wid  = (blockIdx.x * blockDim.x + threadIdx.x) >> 6;
    const int nw   = (gridDim.x * blockDim.x) >> 6;
    const int count = *cnt;

    if (count <= CAND_CAP) {
        for (int c = wid; c < count; c += nw) {
            const unsigned int e = cands[c];
            const int q = (int)(e >> 15), n = (int)(e & 32767u);
            const float2 qv = ((const float2*)(Q + (size_t)q * KD))[lane];
            const float2 kv = ((const float2*)(Kb + (size_t)n * KD))[lane];
            float dot = qv.x * kv.x + qv.y * kv.y;
            float ss  = kv.x * kv.x + kv.y * kv.y;
            #pragma unroll
            for (int m = 32; m; m >>= 1) { dot += __shfl_xor(dot, m); ss += __shfl_xor(ss, m); }
            const float v = dot / fmaxf(sqrtf(ss), 1e-12f);
            if (lane == 0) {
                const unsigned long long p =
                    ((unsigned long long)ord_f32(v) << 32) | (unsigned int)(~n);
                atomicMax(&best2[q], p);
            }
        }
    } else {
        // overflow safety net (never taken for the fixed bench inputs): exhaustive
        for (int q = wid; q < B_Q; q += nw) {
            const float* qr = Q + (size_t)q * KD;
            unsigned long long pb = 0ull;
            for (int n = lane; n < N_SLOTS; n += 64) {
                const float* kr = Kb + (size_t)n * KD;
                float dot = 0.f, ss = 0.f;
                for (int d = 0; d < KD; ++d) {
                    const float kvv = kr[d];
                    dot = fmaf(qr[d], kvv, dot);
                    ss  = fmaf(kvv, kvv, ss);
                }
                const float v = dot / fmaxf(sqrtf(ss), 1e-12f);
                const unsigned long long p =
                    ((unsigned long long)ord_f32(v) << 32) | (unsigned int)(~n);
                if (p > pb) pb = p;
            }
            #pragma unroll
            for (int m = 32; m; m >>= 1) {
                const unsigned long long o = shfl_xor_u64(pb, m, 64);
                if (o > pb) pb = o;
            }
            if (lane == 0) atomicMax(&best2[q], pb);
        }
    }
}

// ---------------- decode ----------------
__global__ void decode_kernel(const unsigned long long* __restrict__ best2,
                              int* __restrict__ out) {
    int i = blockIdx.x * blockDim.x + threadIdx.x;
    if (i < B_Q) out[i] = (int)(~(unsigned int)(best2[i] & 0xFFFFFFFFull));
}

// ---------------- ws-too-small fallback: slow but correct ----------------
__global__ void fallback_kernel(const float* __restrict__ Q, const float* __restrict__ Kb,
                                int* __restrict__ out) {
    __shared__ float q[KD];
    __shared__ unsigned long long red[256];
    const int b = blockIdx.x;
    for (int i = threadIdx.x; i < KD; i += 256) q[i] = Q[(size_t)b * KD + i];
    __syncthreads();
    unsigned long long pbest = 0ull;
    for (int n = threadIdx.x; n < N_SLOTS; n += 256) {
        const float* kr = Kb + (size_t)n * KD;
        float dot = 0.f, ss = 0.f;
        for (int d = 0; d < KD; ++d) { float kv = kr[d]; dot = fmaf(q[d], kv, dot); ss = fmaf(kv, kv, ss); }
        float v = dot / fmaxf(sqrtf(ss), 1e-12f);
        unsigned long long p = ((unsigned long long)ord_f32(v) << 32) | (unsigned int)(~n);
        if (p > pbest) pbest = p;
    }
    red[threadIdx.x] = pbest; __syncthreads();
    for (int s = 128; s; s >>= 1) {
        if (threadIdx.x < (unsigned)s && red[threadIdx.x + s] > red[threadIdx.x])
            red[threadIdx.x] = red[threadIdx.x + s];
        __syncthreads();
    }
    if (threadIdx.x == 0) out[b] = (int)(~(unsigned int)(red[0] & 0xFFFFFFFFull));
}

extern "C" void kernel_launch(void* const* d_in, const int* in_sizes, int n_in,
                              void* d_out, int out_size, void* d_ws, size_t ws_size,
                              hipStream_t stream) {
    const float* Q  = (const float*)d_in[0];   // 4096 x 128
    const float* Kb = (const float*)d_in[1];   // 32768 x 128
    int* out = (int*)d_out;

    const size_t QH_B = (size_t)B_Q * KD * 2;        // 1 MB
    const size_t KH_B = (size_t)N_SLOTS * KD * 2;    // 8 MB
    const size_t GLB_B = (size_t)B_Q * 4;            // 16 KB
    const size_t B2_B  = (size_t)B_Q * 8;            // 32 KB
    const size_t CNT_B = 256;
    const size_t CND_B = (size_t)CAND_CAP * 4;       // 8 MB
    const size_t NEED = QH_B + KH_B + GLB_B + B2_B + CNT_B + CND_B;

    if (ws_size < NEED) {
        fallback_kernel<<<B_Q, 256, 0, stream>>>(Q, Kb, out);
        return;
    }

    char* p = (char*)d_ws;
    unsigned short* qhi = (unsigned short*)p;            p += QH_B;
    unsigned short* khi = (unsigned short*)p;            p += KH_B;
    unsigned int*   glb = (unsigned int*)p;              p += GLB_B;
    unsigned long long* best2 = (unsigned long long*)p;  p += B2_B;
    int*            cnt = (int*)p;                       p += CNT_B;
    unsigned int*   cands = (unsigned int*)p;

    hipMemsetAsync(glb, 0, GLB_B + B2_B + CNT_B, stream);  // glb, best2, cnt contiguous
    prep_kernel<<<(N_SLOTS + B_Q) / 4, 256, 0, stream>>>(Q, Kb, qhi, khi);
    pass1_kernel<<<dim3(B_Q / BM, NSPLIT), 256, 0, stream>>>(qhi, khi, glb, cnt, cands);
    pass2_kernel<<<1024, 256, 0, stream>>>(Q, Kb, cnt, cands, best2);
    decode_kernel<<<B_Q / 256, 256, 0, stream>>>(best2, out);
}

// Round 5
// 150.016 us; speedup vs baseline: 37.5010x; 37.5010x over previous
//
#include <hip/hip_runtime.h>
#include <stdint.h>

#define B_Q     4096
#define N_SLOTS 32768
#define KD      128
#define BM      128
#define BN      128
#define NSPLIT  16
#define NCHUNK  (N_SLOTS / NSPLIT)   // 2048 cols per block
#define NT_BLK  (NCHUNK / BN)        // 16 tiles per block
#define CAND_CAP (1 << 21)           // 2M global candidate cap
#define LCAP    6144                 // per-block LDS candidate cap

typedef _Float16 f16x8 __attribute__((ext_vector_type(8)));
typedef float    f32x4 __attribute__((ext_vector_type(4)));

__device__ __forceinline__ unsigned short h_bits(float x) {
    _Float16 h = (_Float16)x;        // v_cvt_f16_f32, RNE
    unsigned short b;
    __builtin_memcpy(&b, &h, 2);
    return b;
}

// ordered-float: monotone f32 <-> u32
__device__ __forceinline__ unsigned int ord_f32(float f) {
    unsigned int u = __float_as_uint(f);
    return (u & 0x80000000u) ? ~u : (u | 0x80000000u);
}

__device__ __forceinline__ unsigned long long shfl_xor_u64(unsigned long long v, int mask, int width) {
    unsigned int lo = (unsigned int)v, hi = (unsigned int)(v >> 32);
    lo = __shfl_xor(lo, mask, width);
    hi = __shfl_xor(hi, mask, width);
    return ((unsigned long long)hi << 32) | lo;
}

// max over the 16-lane DPP row via 4x ROW_ROR rotate-reduce (no LDS traffic)
__device__ __forceinline__ float rowmax16(float x) {
    x = fmaxf(x, __int_as_float(__builtin_amdgcn_mov_dpp(__float_as_int(x), 0x128, 0xf, 0xf, true)));
    x = fmaxf(x, __int_as_float(__builtin_amdgcn_mov_dpp(__float_as_int(x), 0x124, 0xf, 0xf, true)));
    x = fmaxf(x, __int_as_float(__builtin_amdgcn_mov_dpp(__float_as_int(x), 0x122, 0xf, 0xf, true)));
    x = fmaxf(x, __int_as_float(__builtin_amdgcn_mov_dpp(__float_as_int(x), 0x121, 0xf, 0xf, true)));
    return x;
}

__device__ __forceinline__ void gload_lds16(const void* g, void* l) {
    __builtin_amdgcn_global_load_lds(
        (const __attribute__((address_space(1))) unsigned int*)g,
        (__attribute__((address_space(3))) unsigned int*)l, 16, 0, 0);
}

// ---------------- prep: K -> normalized f16 + invk; Q -> f16 + per-row margin ----------------
// one wave per row; also zeroes best2/cnt (replaces memset dispatch)
__global__ void prep_kernel(const float* __restrict__ Q, const float* __restrict__ Kb,
                            unsigned short* __restrict__ qh, unsigned short* __restrict__ kh,
                            float* __restrict__ marg, float* __restrict__ invk,
                            unsigned long long* __restrict__ best2, int* __restrict__ cnt) {
    const int gid = blockIdx.x * blockDim.x + threadIdx.x;
    if (gid < B_Q) best2[gid] = 0ull;
    if (gid == 0) { cnt[0] = 0; cnt[1] = 0; }

    const int wid  = blockIdx.x * 4 + (threadIdx.x >> 6);
    const int lane = threadIdx.x & 63;
    const bool isK = wid < N_SLOTS;
    const int row  = isK ? wid : wid - N_SLOTS;
    const float* src = isK ? Kb : Q;
    float2 v = reinterpret_cast<const float2*>(src + (size_t)row * KD)[lane];
    float ss = v.x * v.x + v.y * v.y;
    #pragma unroll
    for (int off = 32; off; off >>= 1) ss += __shfl_xor(ss, off);
    const float nrm = fmaxf(sqrtf(ss), 1e-12f);
    float scale = 1.0f;
    if (isK) {
        scale = 1.0f / nrm;
        if (lane == 0) invk[row] = scale;
    } else {
        // deterministic margin: 2 * 2^-12 * ||q||  (+44% slack for accum/normalize rounding)
        if (lane == 0) marg[row] = nrm * 1.5e-3f;
    }
    const unsigned short hx = h_bits(v.x * scale), hy = h_bits(v.y * scale);
    unsigned short* dh = isK ? kh : qh;
    ((unsigned int*)(dh + (size_t)row * KD))[lane] = (unsigned int)hx | ((unsigned int)hy << 16);
}

// ---------------- pass 1: f16 GEMM + margin-candidate collection ----------------
// grid (32,16), block 256 = 4 waves (2x2 quadrants of 64x64). Q frags in registers.
// K tile [128 n-rows][128 k] f16 in LDS; 16B slot s of row r holds logical chunk
// s^(r&7) (pre-swizzled global source; linear LDS dest per rule 21).
__global__ __launch_bounds__(256, 2) void pass1_kernel(
    const unsigned short* __restrict__ qh, const unsigned short* __restrict__ kh,
    const float* __restrict__ marg,
    int* __restrict__ cnt, unsigned int* __restrict__ cands)
{
    __shared__ unsigned char lds[32768];
    __shared__ unsigned int lbuf[LCAP];
    __shared__ int lcnt;
    __shared__ int sbase;

    const int tid  = threadIdx.x;
    const int lane = tid & 63;
    const int w    = tid >> 6;
    const int wr   = w >> 1;
    const int wc   = w & 1;
    const int q0   = blockIdx.x * BM;
    const int n0   = blockIdx.y * NCHUNK;
    const int l15  = lane & 15;
    const int lg   = lane >> 4;

    if (tid == 0) lcnt = 0;

    // per-lane owned rows: row(e) = q0 + wr*64 + (e>>2)*16 + lg*4 + (e&3)
    float L[16], mg[16];
    #pragma unroll
    for (int e = 0; e < 16; ++e) {
        const int row = q0 + wr * 64 + (e >> 2) * 16 + lg * 4 + (e & 3);
        mg[e] = marg[row];
        L[e]  = -3e38f;
    }

    // Q fragments in registers: row = q0+wr*64+i*16+l15, k = kc*32 + lg*8 .. +8
    f16x8 aq[4][4];
    #pragma unroll
    for (int i = 0; i < 4; ++i)
        #pragma unroll
        for (int kc = 0; kc < 4; ++kc)
            aq[i][kc] = *(const f16x8*)(qh + (size_t)(q0 + wr * 64 + i * 16 + l15) * KD
                                        + kc * 32 + lg * 8);

    #pragma unroll 1
    for (int t = 0; t < NT_BLK; ++t) {
        const int nb = n0 + t * BN;
        __syncthreads();                 // previous tile's LDS reads done (orders lcnt init too)
        #pragma unroll
        for (int it = 0; it < 8; ++it) { // stage K tile: 32 KB
            const int ch = it * 256 + tid;
            const int r  = ch >> 4;
            const int lchunk = (ch & 15) ^ (r & 7);   // inverse swizzle on source
            gload_lds16(kh + (size_t)(nb + r) * KD + lchunk * 8, &lds[ch * 16]);
        }
        __syncthreads();                 // vmcnt drained by compiler before barrier

        f32x4 acc[4][4];
        #pragma unroll
        for (int i = 0; i < 4; ++i)
            #pragma unroll
            for (int j = 0; j < 4; ++j) {
                acc[i][j][0] = 0.f; acc[i][j][1] = 0.f;
                acc[i][j][2] = 0.f; acc[i][j][3] = 0.f;
            }

        #pragma unroll
        for (int kc = 0; kc < 4; ++kc) {
            f16x8 bh[4];
            #pragma unroll
            for (int j = 0; j < 4; ++j) {
                const int rb = wc * 64 + j * 16 + l15;
                const int ps = (kc * 4 + lg) ^ (rb & 7);   // physical 16B slot
                bh[j] = *(const f16x8*)&lds[rb * 256 + ps * 16];
            }
            #pragma unroll
            for (int i = 0; i < 4; ++i)
                #pragma unroll
                for (int j = 0; j < 4; ++j)
                    acc[i][j] = __builtin_amdgcn_mfma_f32_16x16x32_f16(aq[i][kc], bh[j], acc[i][j], 0, 0, 0);
        }

        // fold current tile into running row-max, share across the 16 lanes via DPP
        #pragma unroll
        for (int e = 0; e < 16; ++e) {
            const int i = e >> 2, r = e & 3;
            float Le = fmaxf(L[e],
                fmaxf(fmaxf(acc[i][0][r], acc[i][1][r]), fmaxf(acc[i][2][r], acc[i][3][r])));
            L[e] = rowmax16(Le);
        }

        // append candidates >= rowmax - margin into LDS buffer (rare)
        #pragma unroll
        for (int e = 0; e < 16; ++e) {
            const int i = e >> 2, r = e & 3;
            const float th = L[e] - mg[e];
            const int row = q0 + wr * 64 + i * 16 + lg * 4 + r;
            #pragma unroll
            for (int j = 0; j < 4; ++j) {
                if (acc[i][j][r] >= th) {
                    const int n = nb + wc * 64 + j * 16 + l15;
                    const int pos = atomicAdd(&lcnt, 1);
                    if (pos < LCAP) lbuf[pos] = ((unsigned int)row << 15) | (unsigned int)n;
                }
            }
        }
    }

    // flush: ONE global atomic per block
    __syncthreads();
    const int total = lcnt;
    const int nout  = total < LCAP ? total : LCAP;
    if (tid == 0) {
        const int base = atomicAdd(&cnt[0], nout);
        sbase = base;
        if (total > LCAP || base + nout > CAND_CAP) atomicOr(&cnt[1], 1);
    }
    __syncthreads();
    for (int c = tid; c < nout; c += 256) {
        const int g = sbase + c;
        if (g < CAND_CAP) cands[g] = lbuf[c];
    }
}

// ---------------- pass 2: exact fp32 rescore, 16 lanes per candidate ----------------
__global__ void pass2_kernel(const float* __restrict__ Q, const float* __restrict__ Kb,
                             const float* __restrict__ invk,
                             const int* __restrict__ cnt, const unsigned int* __restrict__ cands,
                             unsigned long long* __restrict__ best2) {
    const int lane = threadIdx.x & 63;
    const int l15  = lane & 15;
    const int grp  = lane >> 4;
    const int wid  = (blockIdx.x * blockDim.x + threadIdx.x) >> 6;
    const int ngrp = ((gridDim.x * blockDim.x) >> 6) * 4;
    const int count = cnt[0];
    const bool bad = (cnt[1] != 0) || (count > CAND_CAP);

    if (!bad) {
        for (int c = wid * 4 + grp; c < count; c += ngrp) {
            const unsigned int e = cands[c];
            const int q = (int)(e >> 15), n = (int)(e & 32767u);
            const float4* qp = (const float4*)(Q  + (size_t)q * KD);
            const float4* kp = (const float4*)(Kb + (size_t)n * KD);
            const float4 qa = qp[l15 * 2], qb = qp[l15 * 2 + 1];
            const float4 ka = kp[l15 * 2], kb = kp[l15 * 2 + 1];
            float dot = qa.x * ka.x + qa.y * ka.y + qa.z * ka.z + qa.w * ka.w
                      + qb.x * kb.x + qb.y * kb.y + qb.z * kb.z + qb.w * kb.w;
            #pragma unroll
            for (int m = 8; m; m >>= 1) dot += __shfl_xor(dot, m, 16);
            if (l15 == 0) {
                const float v = dot * invk[n];
                const unsigned long long p =
                    ((unsigned long long)ord_f32(v) << 32) | (unsigned int)(~n);
                atomicMax(&best2[q], p);
            }
        }
    } else {
        // overflow safety net (never taken for bench inputs): exhaustive, correct
        for (int q = wid; q < B_Q; q += ngrp / 4) {
            const float* qr = Q + (size_t)q * KD;
            unsigned long long pb = 0ull;
            for (int n = lane; n < N_SLOTS; n += 64) {
                const float* kr = Kb + (size_t)n * KD;
                float dot = 0.f;
                for (int d = 0; d < KD; ++d) dot = fmaf(qr[d], kr[d], dot);
                const float v = dot * invk[n];
                const unsigned long long p =
                    ((unsigned long long)ord_f32(v) << 32) | (unsigned int)(~n);
                if (p > pb) pb = p;
            }
            #pragma unroll
            for (int m = 32; m; m >>= 1) {
                const unsigned long long o = shfl_xor_u64(pb, m, 64);
                if (o > pb) pb = o;
            }
            if (lane == 0) atomicMax(&best2[q], pb);
        }
    }
}

// ---------------- decode ----------------
__global__ void decode_kernel(const unsigned long long* __restrict__ best2,
                              int* __restrict__ out) {
    int i = blockIdx.x * blockDim.x + threadIdx.x;
    if (i < B_Q) out[i] = (int)(~(unsigned int)(best2[i] & 0xFFFFFFFFull));
}

// ---------------- ws-too-small fallback: slow but correct ----------------
__global__ void fallback_kernel(const float* __restrict__ Q, const float* __restrict__ Kb,
                                int* __restrict__ out) {
    __shared__ float q[KD];
    __shared__ unsigned long long red[256];
    const int b = blockIdx.x;
    for (int i = threadIdx.x; i < KD; i += 256) q[i] = Q[(size_t)b * KD + i];
    __syncthreads();
    unsigned long long pbest = 0ull;
    for (int n = threadIdx.x; n < N_SLOTS; n += 256) {
        const float* kr = Kb + (size_t)n * KD;
        float dot = 0.f, ss = 0.f;
        for (int d = 0; d < KD; ++d) { float kv = kr[d]; dot = fmaf(q[d], kv, dot); ss = fmaf(kv, kv, ss); }
        float v = dot / fmaxf(sqrtf(ss), 1e-12f);
        unsigned long long p = ((unsigned long long)ord_f32(v) << 32) | (unsigned int)(~n);
        if (p > pbest) pbest = p;
    }
    red[threadIdx.x] = pbest; __syncthreads();
    for (int s = 128; s; s >>= 1) {
        if (threadIdx.x < (unsigned)s && red[threadIdx.x + s] > red[threadIdx.x])
            red[threadIdx.x] = red[threadIdx.x + s];
        __syncthreads();
    }
    if (threadIdx.x == 0) out[b] = (int)(~(unsigned int)(red[0] & 0xFFFFFFFFull));
}

extern "C" void kernel_launch(void* const* d_in, const int* in_sizes, int n_in,
                              void* d_out, int out_size, void* d_ws, size_t ws_size,
                              hipStream_t stream) {
    const float* Q  = (const float*)d_in[0];   // 4096 x 128
    const float* Kb = (const float*)d_in[1];   // 32768 x 128
    int* out = (int*)d_out;

    const size_t QH_B = (size_t)B_Q * KD * 2;        // 1 MB
    const size_t KH_B = (size_t)N_SLOTS * KD * 2;    // 8 MB
    const size_t MG_B = (size_t)B_Q * 4;             // 16 KB
    const size_t IK_B = (size_t)N_SLOTS * 4;         // 128 KB
    const size_t B2_B = (size_t)B_Q * 8;             // 32 KB
    const size_t CNT_B = 256;
    const size_t CND_B = (size_t)CAND_CAP * 4;       // 8 MB
    const size_t NEED = QH_B + KH_B + MG_B + IK_B + B2_B + CNT_B + CND_B;

    if (ws_size < NEED) {
        fallback_kernel<<<B_Q, 256, 0, stream>>>(Q, Kb, out);
        return;
    }

    char* p = (char*)d_ws;
    unsigned short* qh = (unsigned short*)p;             p += QH_B;
    unsigned short* kh = (unsigned short*)p;             p += KH_B;
    float*          mg = (float*)p;                      p += MG_B;
    float*          ik = (float*)p;                      p += IK_B;
    unsigned long long* best2 = (unsigned long long*)p;  p += B2_B;
    int*            cnt = (int*)p;                       p += CNT_B;
    unsigned int*   cands = (unsigned int*)p;

    prep_kernel<<<(N_SLOTS + B_Q) / 4, 256, 0, stream>>>(Q, Kb, qh, kh, mg, ik, best2, cnt);
    pass1_kernel<<<dim3(B_Q / BM, NSPLIT), 256, 0, stream>>>(qh, kh, mg, cnt, cands);
    pass2_kernel<<<1024, 256, 0, stream>>>(Q, Kb, ik, cnt, cands, best2);
    decode_kernel<<<B_Q / 256, 256, 0, stream>>>(best2, out);
}